// Round 2
// baseline (112.420 us; speedup 1.0000x reference)
//
#include <hip/hip_runtime.h>
#include <hip/hip_bf16.h>
#include <math.h>

#define DIN 512
#define DF 256
#define LSEQ 1024
#define NTOT 8192

typedef __attribute__((ext_vector_type(8))) short short8;
typedef __attribute__((ext_vector_type(4))) short short4v;
typedef __attribute__((ext_vector_type(4))) float f32x4;

__device__ __forceinline__ short f2bf(float x) {
  union { float f; unsigned u; } un; un.f = x;
  unsigned r = un.u + 0x7fffu + ((un.u >> 16) & 1u);  // RNE (inputs finite)
  return (short)(r >> 16);
}
__device__ __forceinline__ float bf2f(short s) {
  union { unsigned u; float f; } un; un.u = ((unsigned)(unsigned short)s) << 16;
  return un.f;
}

typedef __attribute__((address_space(1))) const unsigned char AS1c;
typedef __attribute__((address_space(3))) unsigned char AS3;
__device__ __forceinline__ void gload16(const void* g, void* l) {
  __builtin_amdgcn_global_load_lds((AS1c*)g, (AS3*)l, 16, 0, 0);
}

// ---------- kernel 1: W [DIN][DF] f32 -> Wt [DF][DIN] bf16 ----------
__global__ __launch_bounds__(256) void prep_w_kernel(const float* __restrict__ W,
                                                     short* __restrict__ Wt) {
  int idx = blockIdx.x * 256 + threadIdx.x;   // over DF*DIN = 131072
  int c = idx >> 9;            // / DIN
  int k = idx & (DIN - 1);
  Wt[idx] = f2bf(W[(size_t)k * DF + c]);
}

// ---------- kernel 2: projection emb = relu(feat @ W + b), bf16 out ----------
#define PBM 64
#define PBK 32
#define PPAD 40

__global__ __launch_bounds__(256) void proj_kernel(const float* __restrict__ f1,
                                                   const float* __restrict__ f2,
                                                   const short* __restrict__ Wt,
                                                   const float* __restrict__ bias,
                                                   short* __restrict__ emb1,
                                                   short* __restrict__ emb2) {
  const float* feat = blockIdx.y ? f2 : f1;
  short* emb = blockIdx.y ? emb2 : emb1;
  __shared__ short ldsA[PBM * PPAD];
  __shared__ short ldsB[DF * PPAD];
  const int tid = threadIdx.x;
  const int lane = tid & 63, wv = tid >> 6;
  const int wrow = (wv & 1) * 32, wcol = (wv >> 1) * 128;
  const int l15 = lane & 15, lk = (lane >> 4) * 8;
  const int rowbase = blockIdx.x * PBM;

  f32x4 acc[2][8];
#pragma unroll
  for (int mi = 0; mi < 2; ++mi)
#pragma unroll
    for (int nf = 0; nf < 8; ++nf) acc[mi][nf] = f32x4{0.f, 0.f, 0.f, 0.f};

  for (int kb = 0; kb < DIN; kb += PBK) {
    __syncthreads();
#pragma unroll
    for (int i = 0; i < 2; ++i) {
      int flat = tid * 2 + i;
      int r = flat >> 3, kq = (flat & 7) * 4;
      f32x4 v = *(const f32x4*)(feat + (size_t)(rowbase + r) * DIN + kb + kq);
      short4v h;
      h[0] = f2bf(v[0]); h[1] = f2bf(v[1]); h[2] = f2bf(v[2]); h[3] = f2bf(v[3]);
      *(short4v*)(ldsA + r * PPAD + kq) = h;
    }
#pragma unroll
    for (int i = 0; i < 4; ++i) {
      int flat = tid * 4 + i;
      int c = flat >> 2, kq = (flat & 3) * 8;
      short8 v = *(const short8*)(Wt + (size_t)c * DIN + kb + kq);
      *(short8*)(ldsB + c * PPAD + kq) = v;
    }
    __syncthreads();
    short8 af[2], bf[8];
#pragma unroll
    for (int mi = 0; mi < 2; ++mi)
      af[mi] = *(const short8*)(ldsA + (wrow + mi * 16 + l15) * PPAD + lk);
#pragma unroll
    for (int nf = 0; nf < 8; ++nf)
      bf[nf] = *(const short8*)(ldsB + (wcol + nf * 16 + l15) * PPAD + lk);
#pragma unroll
    for (int mi = 0; mi < 2; ++mi)
#pragma unroll
      for (int nf = 0; nf < 8; ++nf)
        acc[mi][nf] = __builtin_amdgcn_mfma_f32_16x16x32_bf16(af[mi], bf[nf], acc[mi][nf], 0, 0, 0);
  }
  const int r4 = (lane >> 4) * 4;
#pragma unroll
  for (int mi = 0; mi < 2; ++mi) {
    int row0 = rowbase + wrow + mi * 16 + r4;
#pragma unroll
    for (int nf = 0; nf < 8; ++nf) {
      int col = wcol + nf * 16 + l15;
      float bb = bias[col];
#pragma unroll
      for (int r = 0; r < 4; ++r) {
        float v = acc[mi][nf][r] + bb;
        v = v > 0.f ? v : 0.f;
        emb[(size_t)(row0 + r) * DF + col] = f2bf(v);
      }
    }
  }
}

// ---------- kernel 3: positive = dot(e1,e2) + banded diag means ----------
__global__ __launch_bounds__(64) void positive_kernel(const short* __restrict__ emb1,
                                                      const short* __restrict__ emb2,
                                                      const int* __restrict__ prs,
                                                      const int* __restrict__ prt,
                                                      float* __restrict__ pos) {
  const int row = blockIdx.x;
  const int b = row >> 10, j = row & (LSEQ - 1);
  const int lane = threadIdx.x;
  const int rs = prs[0], rt = prt[0];
  float a1[4], a2[4];
  {
    short4v v1 = *(const short4v*)(emb1 + (size_t)row * DF + lane * 4);
    short4v v2 = *(const short4v*)(emb2 + (size_t)row * DF + lane * 4);
#pragma unroll
    for (int i = 0; i < 4; ++i) { a1[i] = bf2f(v1[i]); a2[i] = bf2f(v2[i]); }
  }
  float dot12 = 0.f, p11 = 0.f, p22 = 0.f, p12 = 0.f;
#pragma unroll
  for (int i = 0; i < 4; ++i) dot12 += a1[i] * a2[i];
  int rmax = rs > rt ? rs : rt;
  for (int d = -rmax; d <= rmax; ++d) {
    int k = j + d;
    if (k < 0 || k >= LSEQ) continue;
    size_t koff = (size_t)(b * LSEQ + k) * DF + lane * 4;
    short4v w1 = *(const short4v*)(emb1 + koff);
    short4v w2 = *(const short4v*)(emb2 + koff);
    float d11 = 0.f, d22 = 0.f, d12 = 0.f;
#pragma unroll
    for (int i = 0; i < 4; ++i) {
      float e1k = bf2f(w1[i]), e2k = bf2f(w2[i]);
      d11 += a1[i] * e1k;
      d22 += a2[i] * e2k;
      d12 += a1[i] * e2k;
    }
    if (d >= -rs && d <= rs) { p11 += d11; p22 += d22; }
    if (d >= -rt && d <= rt) { p12 += d12; }
  }
#pragma unroll
  for (int m = 1; m < 64; m <<= 1) {
    dot12 += __shfl_xor(dot12, m);
    p11 += __shfl_xor(p11, m);
    p22 += __shfl_xor(p22, m);
    p12 += __shfl_xor(p12, m);
  }
  if (lane == 0) {
    float res = dot12;
    if (rs > 0) {
      int lo = j - rs < 0 ? 0 : j - rs;
      int hi = j + rs > LSEQ - 1 ? LSEQ - 1 : j + rs;
      res += (p11 + p22) / (float)(hi - lo + 1);
    }
    if (rt > 0) {
      int lo = j - rt < 0 ? 0 : j - rt;
      int hi = j + rt > LSEQ - 1 ? LSEQ - 1 : j + rt;
      res += p12 / (float)(hi - lo + 1);
    }
    pos[row] = res;
  }
}

// ---------- kernel 4: flash-style row logsumexp of e1 @ e2^T ----------
// 256 rows/block (4 waves x 64 rows), A (K=256) in registers -> 64 FLOP/LDS-byte.
// B tiles (64 cols) staged via global_load_lds (pre-swizzled source, linear LDS dest),
// read with slot = kblk ^ (c&31). Double-buffered, ONE barrier per tile.
#define NBM 256
#define NBN 64
#define NCHUNK 16
#define CHW (NTOT / NCHUNK)   // 512
#define NT (CHW / NBN)        // 8

__global__ __launch_bounds__(256, 2) void negative_kernel(const short* __restrict__ e1,
                                                          const short* __restrict__ e2,
                                                          float* __restrict__ mpart,
                                                          float* __restrict__ spart) {
  __shared__ short ldsB[2][NBN * DF];   // 2 x 32KB
  const int tid = threadIdx.x;
  const int lane = tid & 63, wv = tid >> 6;
  const int l15 = lane & 15, lk16 = lane >> 4;
  const int rowbase = blockIdx.x * NBM + wv * 64;
  const int chunk = blockIdx.y;
  const short* colbase = e2 + (size_t)(chunk * CHW) * DF;

  // A fragments: 4 m-frags x 8 k-steps, full K=256, register-resident (128 VGPR)
  short8 a[4][8];
#pragma unroll
  for (int mi = 0; mi < 4; ++mi)
#pragma unroll
    for (int ks = 0; ks < 8; ++ks)
      a[mi][ks] = *(const short8*)(e1 + (size_t)(rowbase + mi * 16 + l15) * DF + ks * 32 + lk16 * 8);

  float mrun[16], srun[16];
#pragma unroll
  for (int i = 0; i < 16; ++i) { mrun[i] = -1e30f; srun[i] = 0.f; }

  // prologue: stage tile 0 into buf 0 (LDS slot L holds e2[col c][kblk = (L&31)^(c&31)])
#pragma unroll
  for (int i = 0; i < 8; ++i) {
    int L = i * 256 + tid;
    int c = L >> 5, s = L & 31;
    int kblk = s ^ (c & 31);
    gload16(colbase + (size_t)c * DF + kblk * 8, (short*)ldsB[0] + (i * 256 + wv * 64) * 8);
  }
  __syncthreads();   // compiler drains vmcnt(0) before s_barrier

  for (int t = 0; t < NT; ++t) {
    short* buf = (short*)ldsB[t & 1];
    if (t + 1 < NT) {   // issue next-tile stage BEFORE compute; barrier drain covers it
      const short* nb = colbase + (size_t)(t + 1) * NBN * DF;
      short* dbuf = (short*)ldsB[(t + 1) & 1];
#pragma unroll
      for (int i = 0; i < 8; ++i) {
        int L = i * 256 + tid;
        int c = L >> 5, s = L & 31;
        int kblk = s ^ (c & 31);
        gload16(nb + (size_t)c * DF + kblk * 8, dbuf + (i * 256 + wv * 64) * 8);
      }
    }
    f32x4 acc[4][4];
#pragma unroll
    for (int mi = 0; mi < 4; ++mi)
#pragma unroll
      for (int nf = 0; nf < 4; ++nf) acc[mi][nf] = f32x4{0.f, 0.f, 0.f, 0.f};
#pragma unroll
    for (int ks = 0; ks < 8; ++ks) {
      short8 bfr[4];
#pragma unroll
      for (int nf = 0; nf < 4; ++nf) {
        int c = nf * 16 + l15;
        int kblk = ks * 4 + lk16;
        int s = kblk ^ (c & 31);
        bfr[nf] = *(const short8*)(buf + (c * 32 + s) * 8);
      }
#pragma unroll
      for (int mi = 0; mi < 4; ++mi)
#pragma unroll
        for (int nf = 0; nf < 4; ++nf)
          acc[mi][nf] = __builtin_amdgcn_mfma_f32_16x16x32_bf16(a[mi][ks], bfr[nf], acc[mi][nf], 0, 0, 0);
    }
    // online softmax, defer-max (THR=8): P bounded by e^8, srun <= 8192*e^8 << f32 max
#pragma unroll
    for (int mi = 0; mi < 4; ++mi)
#pragma unroll
      for (int r = 0; r < 4; ++r) {
        int s8 = mi * 4 + r;
        float v0 = acc[mi][0][r], v1 = acc[mi][1][r], v2 = acc[mi][2][r], v3 = acc[mi][3][r];
        float mx = fmaxf(fmaxf(v0, v1), fmaxf(v2, v3));
        float mo = mrun[s8];
        if (mx > mo + 8.f) {
          srun[s8] *= __expf(mo - mx);
          mo = mx;
          mrun[s8] = mx;
        }
        srun[s8] += __expf(v0 - mo) + __expf(v1 - mo) + __expf(v2 - mo) + __expf(v3 - mo);
      }
    __syncthreads();
  }
  // merge (m,s) across the 16 lanes holding each row, write per-chunk partials
#pragma unroll
  for (int mi = 0; mi < 4; ++mi)
#pragma unroll
    for (int r = 0; r < 4; ++r) {
      int s8 = mi * 4 + r;
      float m = mrun[s8], s = srun[s8];
#pragma unroll
      for (int msk = 1; msk < 16; msk <<= 1) {
        float mo = __shfl_xor(m, msk);
        float so = __shfl_xor(s, msk);
        float mn = fmaxf(m, mo);
        s = s * __expf(m - mn) + so * __expf(mo - mn);
        m = mn;
      }
      if (l15 == 0) {
        int row = rowbase + mi * 16 + lk16 * 4 + r;
        mpart[chunk * NTOT + row] = m;
        spart[chunk * NTOT + row] = s;
      }
    }
}

// ---------- kernel 5a: per-row lse - pos, block partial sums (32 blocks) ----------
__global__ __launch_bounds__(256) void finalize1_kernel(const float* __restrict__ pos,
                                                        const float* __restrict__ mpart,
                                                        const float* __restrict__ spart,
                                                        float* __restrict__ partial) {
  __shared__ float red[4];
  int row = blockIdx.x * 256 + threadIdx.x;
  float m = -1e30f;
#pragma unroll
  for (int c = 0; c < NCHUNK; ++c) m = fmaxf(m, mpart[c * NTOT + row]);
  float s = 0.f;
#pragma unroll
  for (int c = 0; c < NCHUNK; ++c) s += spart[c * NTOT + row] * __expf(mpart[c * NTOT + row] - m);
  float v = m + logf(s) - pos[row];
#pragma unroll
  for (int msk = 1; msk < 64; msk <<= 1) v += __shfl_xor(v, msk);
  if ((threadIdx.x & 63) == 0) red[threadIdx.x >> 6] = v;
  __syncthreads();
  if (threadIdx.x == 0) partial[blockIdx.x] = red[0] + red[1] + red[2] + red[3];
}

// ---------- kernel 5b: final scalar ----------
__global__ __launch_bounds__(64) void finalize2_kernel(const float* __restrict__ partial,
                                                       float* __restrict__ out) {
  int lane = threadIdx.x;
  float v = lane < 32 ? partial[lane] : 0.f;
#pragma unroll
  for (int msk = 1; msk < 64; msk <<= 1) v += __shfl_xor(v, msk);
  if (lane == 0) out[0] = v / (float)NTOT - logf((float)NTOT);
}

extern "C" void kernel_launch(void* const* d_in, const int* in_sizes, int n_in,
                              void* d_out, int out_size, void* d_ws, size_t ws_size,
                              hipStream_t stream) {
  const float* f1 = (const float*)d_in[0];
  const float* f2 = (const float*)d_in[1];
  const float* W = (const float*)d_in[2];
  const float* bias = (const float*)d_in[3];
  const int* prs = (const int*)d_in[4];
  const int* prt = (const int*)d_in[5];
  float* out = (float*)d_out;

  char* ws = (char*)d_ws;
  short* Wt = (short*)(ws);                                  // 256 KB @ 0
  short* emb1 = (short*)(ws + 262144);                       // 4 MB
  short* emb2 = (short*)(ws + 262144 + 4194304);             // 4 MB
  float* pos = (float*)(ws + 8650752);                       // 32 KB
  float* mpart = (float*)(ws + 8683520);                     // 512 KB
  float* spart = (float*)(ws + 9207808);                     // 512 KB
  float* partial = (float*)(ws + 9732096);                   // 128 B

  prep_w_kernel<<<(DF * DIN) / 256, 256, 0, stream>>>(W, Wt);
  proj_kernel<<<dim3(NTOT / PBM, 2), 256, 0, stream>>>(f1, f2, Wt, bias, emb1, emb2);
  positive_kernel<<<NTOT, 64, 0, stream>>>(emb1, emb2, prs, prt, pos);
  negative_kernel<<<dim3(NTOT / NBM, NCHUNK), 256, 0, stream>>>(emb1, emb2, mpart, spart);
  finalize1_kernel<<<32, 256, 0, stream>>>(pos, mpart, spart, partial);
  finalize2_kernel<<<1, 64, 0, stream>>>(partial, out);
}

// Round 3
// 107.057 us; speedup vs baseline: 1.0501x; 1.0501x over previous
//
#include <hip/hip_runtime.h>
#include <hip/hip_bf16.h>
#include <math.h>

#define DIN 512
#define DF 256
#define LSEQ 1024
#define NTOT 8192

typedef __attribute__((ext_vector_type(8))) short short8;
typedef __attribute__((ext_vector_type(4))) short short4v;
typedef __attribute__((ext_vector_type(4))) float f32x4;

__device__ __forceinline__ short f2bf(float x) {
  union { float f; unsigned u; } un; un.f = x;
  unsigned r = un.u + 0x7fffu + ((un.u >> 16) & 1u);  // RNE (inputs finite)
  return (short)(r >> 16);
}
__device__ __forceinline__ float bf2f(short s) {
  union { unsigned u; float f; } un; un.u = ((unsigned)(unsigned short)s) << 16;
  return un.f;
}

typedef __attribute__((address_space(1))) const unsigned char AS1c;
typedef __attribute__((address_space(3))) unsigned char AS3;
__device__ __forceinline__ void gload16(const void* g, void* l) {
  __builtin_amdgcn_global_load_lds((AS1c*)g, (AS3*)l, 16, 0, 0);
}
#define CFENCE() asm volatile("" ::: "memory")

// ---------- kernel 1: W [DIN][DF] f32 -> Wt [DF][DIN] bf16 ----------
__global__ __launch_bounds__(256) void prep_w_kernel(const float* __restrict__ W,
                                                     short* __restrict__ Wt) {
  int idx = blockIdx.x * 256 + threadIdx.x;
  int c = idx >> 9;
  int k = idx & (DIN - 1);
  Wt[idx] = f2bf(W[(size_t)k * DF + c]);
}

// ---------- kernel 2: projection emb = relu(feat @ W + b), bf16 out ----------
// BM=64 rows, full 256 cols, BK=64 (8 iters, 2 barriers each). 4 waves 2x2.
#define PBM 64
#define PBK 64
#define PROW 72   // padded LDS row in shorts: 144B stride -> 2-lane/bank (free)

__global__ __launch_bounds__(256) void proj_kernel(const float* __restrict__ f1,
                                                   const float* __restrict__ f2,
                                                   const short* __restrict__ Wt,
                                                   const float* __restrict__ bias,
                                                   short* __restrict__ emb1,
                                                   short* __restrict__ emb2) {
  const float* feat = blockIdx.y ? f2 : f1;
  short* emb = blockIdx.y ? emb2 : emb1;
  __shared__ short ldsA[PBM * PROW];
  __shared__ short ldsB[DF * PROW];
  const int tid = threadIdx.x;
  const int lane = tid & 63, wv = tid >> 6;
  const int wrow = (wv & 1) * 32, wcol = (wv >> 1) * 128;
  const int l15 = lane & 15, lk = (lane >> 4) * 8;
  const int rowbase = blockIdx.x * PBM;

  f32x4 acc[2][8];
#pragma unroll
  for (int mi = 0; mi < 2; ++mi)
#pragma unroll
    for (int nf = 0; nf < 8; ++nf) acc[mi][nf] = f32x4{0.f, 0.f, 0.f, 0.f};

  for (int kb = 0; kb < DIN; kb += PBK) {
    __syncthreads();
    // stage A: 64 rows x 64 k f32 -> bf16 (1024 f32x4 chunks, 4/thread)
#pragma unroll
    for (int i = 0; i < 4; ++i) {
      int flat = tid * 4 + i;
      int r = flat >> 4, kq = (flat & 15) * 4;
      f32x4 v = *(const f32x4*)(feat + (size_t)(rowbase + r) * DIN + kb + kq);
      short4v h;
      h[0] = f2bf(v[0]); h[1] = f2bf(v[1]); h[2] = f2bf(v[2]); h[3] = f2bf(v[3]);
      *(short4v*)(ldsA + r * PROW + kq) = h;
    }
    // stage B: 256 cols x 64 k bf16 (2048 short8 chunks, 8/thread = 128B/thread)
#pragma unroll
    for (int i = 0; i < 8; ++i) {
      int c = tid, kq = i * 8;
      short8 v = *(const short8*)(Wt + (size_t)c * DIN + kb + kq);
      *(short8*)(ldsB + c * PROW + kq) = v;
    }
    __syncthreads();
#pragma unroll
    for (int kk = 0; kk < 2; ++kk) {
      short8 af[2], bf[8];
#pragma unroll
      for (int mi = 0; mi < 2; ++mi)
        af[mi] = *(const short8*)(ldsA + (wrow + mi * 16 + l15) * PROW + kk * 32 + lk);
#pragma unroll
      for (int nf = 0; nf < 8; ++nf)
        bf[nf] = *(const short8*)(ldsB + (wcol + nf * 16 + l15) * PROW + kk * 32 + lk);
#pragma unroll
      for (int mi = 0; mi < 2; ++mi)
#pragma unroll
        for (int nf = 0; nf < 8; ++nf)
          acc[mi][nf] = __builtin_amdgcn_mfma_f32_16x16x32_bf16(af[mi], bf[nf], acc[mi][nf], 0, 0, 0);
    }
  }
  const int r4 = (lane >> 4) * 4;
#pragma unroll
  for (int mi = 0; mi < 2; ++mi) {
    int row0 = rowbase + wrow + mi * 16 + r4;
#pragma unroll
    for (int nf = 0; nf < 8; ++nf) {
      int col = wcol + nf * 16 + l15;
      float bb = bias[col];
#pragma unroll
      for (int r = 0; r < 4; ++r) {
        float v = acc[mi][nf][r] + bb;
        v = v > 0.f ? v : 0.f;
        emb[(size_t)(row0 + r) * DF + col] = f2bf(v);
      }
    }
  }
}

// ---------- kernel 3: positive = dot(e1,e2) + banded diag means ----------
__global__ __launch_bounds__(64) void positive_kernel(const short* __restrict__ emb1,
                                                      const short* __restrict__ emb2,
                                                      const int* __restrict__ prs,
                                                      const int* __restrict__ prt,
                                                      float* __restrict__ pos) {
  const int row = blockIdx.x;
  const int b = row >> 10, j = row & (LSEQ - 1);
  const int lane = threadIdx.x;
  const int rs = prs[0], rt = prt[0];
  float a1[4], a2[4];
  {
    short4v v1 = *(const short4v*)(emb1 + (size_t)row * DF + lane * 4);
    short4v v2 = *(const short4v*)(emb2 + (size_t)row * DF + lane * 4);
#pragma unroll
    for (int i = 0; i < 4; ++i) { a1[i] = bf2f(v1[i]); a2[i] = bf2f(v2[i]); }
  }
  float dot12 = 0.f, p11 = 0.f, p22 = 0.f, p12 = 0.f;
#pragma unroll
  for (int i = 0; i < 4; ++i) dot12 += a1[i] * a2[i];
  int rmax = rs > rt ? rs : rt;
  for (int d = -rmax; d <= rmax; ++d) {
    int k = j + d;
    if (k < 0 || k >= LSEQ) continue;
    size_t koff = (size_t)(b * LSEQ + k) * DF + lane * 4;
    short4v w1 = *(const short4v*)(emb1 + koff);
    short4v w2 = *(const short4v*)(emb2 + koff);
    float d11 = 0.f, d22 = 0.f, d12 = 0.f;
#pragma unroll
    for (int i = 0; i < 4; ++i) {
      float e1k = bf2f(w1[i]), e2k = bf2f(w2[i]);
      d11 += a1[i] * e1k;
      d22 += a2[i] * e2k;
      d12 += a1[i] * e2k;
    }
    if (d >= -rs && d <= rs) { p11 += d11; p22 += d22; }
    if (d >= -rt && d <= rt) { p12 += d12; }
  }
#pragma unroll
  for (int m = 1; m < 64; m <<= 1) {
    dot12 += __shfl_xor(dot12, m);
    p11 += __shfl_xor(p11, m);
    p22 += __shfl_xor(p22, m);
    p12 += __shfl_xor(p12, m);
  }
  if (lane == 0) {
    float res = dot12;
    if (rs > 0) {
      int lo = j - rs < 0 ? 0 : j - rs;
      int hi = j + rs > LSEQ - 1 ? LSEQ - 1 : j + rs;
      res += (p11 + p22) / (float)(hi - lo + 1);
    }
    if (rt > 0) {
      int lo = j - rt < 0 ? 0 : j - rt;
      int hi = j + rt > LSEQ - 1 ? LSEQ - 1 : j + rt;
      res += p12 / (float)(hi - lo + 1);
    }
    pos[row] = res;
  }
}

// ---------- kernel 4: flash-style row logsumexp of e1 @ e2^T ----------
// 256 rows/block (4 waves x 64 rows), A (K=256) register-resident.
// B tiles (64 cols) via global_load_lds, pre-swizzled source, linear LDS dest,
// read with slot = kblk ^ (c&31) (0 bank conflicts, verified R2).
// T4 schedule: 2-deep prefetch, counted s_waitcnt vmcnt(8) + raw s_barrier —
// stage loads stay in flight across barriers (never drain to 0 mid-loop).
#define NBM 256
#define NBN 64
#define NCHUNK 16
#define CHW (NTOT / NCHUNK)   // 512
#define NT (CHW / NBN)        // 8

__global__ __launch_bounds__(256, 2) void negative_kernel(const short* __restrict__ e1,
                                                          const short* __restrict__ e2,
                                                          float* __restrict__ mpart,
                                                          float* __restrict__ spart) {
  __shared__ short ldsB[2][NBN * DF];   // 2 x 32KB
  const int tid = threadIdx.x;
  const int lane = tid & 63, wv = tid >> 6;
  const int l15 = lane & 15, lk16 = lane >> 4;
  const int rowbase = blockIdx.x * NBM + wv * 64;
  const short* colbase = e2 + (size_t)(blockIdx.y * CHW) * DF;

  auto stage = [&](int tt) {
    const short* nb = colbase + (size_t)tt * NBN * DF;
    short* db = (short*)ldsB[tt & 1];
#pragma unroll
    for (int i = 0; i < 8; ++i) {
      int L = i * 256 + tid;
      int c = L >> 5, s = L & 31;
      int kb = s ^ (c & 31);
      gload16(nb + (size_t)c * DF + kb * 8, db + (i * 256 + wv * 64) * 8);
    }
  };

  stage(0);
  CFENCE();
  // A fragments: 4 m-frags x 8 k-steps, full K=256 (issued between stage0/stage1
  // so vmcnt(8) at t=0 implies stage0 + A complete)
  short8 a[4][8];
#pragma unroll
  for (int mi = 0; mi < 4; ++mi)
#pragma unroll
    for (int ks = 0; ks < 8; ++ks)
      a[mi][ks] = *(const short8*)(e1 + (size_t)(rowbase + mi * 16 + l15) * DF + ks * 32 + lk16 * 8);
  CFENCE();
  stage(1);
  CFENCE();

  float mrun[16], srun[16];
#pragma unroll
  for (int i = 0; i < 16; ++i) { mrun[i] = -1e30f; srun[i] = 0.f; }

  for (int t = 0; t < NT; ++t) {
    if (t < NT - 1) asm volatile("s_waitcnt vmcnt(8)" ::: "memory");
    else            asm volatile("s_waitcnt vmcnt(0)" ::: "memory");
    __builtin_amdgcn_sched_barrier(0);
    __builtin_amdgcn_s_barrier();      // buf[t&1] fully staged for all waves
    const short* buf = (const short*)ldsB[t & 1];

    f32x4 acc[4][4];
#pragma unroll
    for (int mi = 0; mi < 4; ++mi)
#pragma unroll
      for (int nf = 0; nf < 4; ++nf) acc[mi][nf] = f32x4{0.f, 0.f, 0.f, 0.f};

#pragma unroll
    for (int nfp = 0; nfp < 2; ++nfp) {
      __builtin_amdgcn_s_setprio(1);
#pragma unroll
      for (int ks = 0; ks < 8; ++ks) {
        int kblk = ks * 4 + lk16;
        int c0 = (2 * nfp) * 16 + l15;
        int c1 = (2 * nfp + 1) * 16 + l15;
        short8 b0 = *(const short8*)(buf + (c0 * 32 + (kblk ^ (c0 & 31))) * 8);
        short8 b1 = *(const short8*)(buf + (c1 * 32 + (kblk ^ (c1 & 31))) * 8);
#pragma unroll
        for (int mi = 0; mi < 4; ++mi) {
          acc[mi][2 * nfp] = __builtin_amdgcn_mfma_f32_16x16x32_bf16(a[mi][ks], b0, acc[mi][2 * nfp], 0, 0, 0);
          acc[mi][2 * nfp + 1] = __builtin_amdgcn_mfma_f32_16x16x32_bf16(a[mi][ks], b1, acc[mi][2 * nfp + 1], 0, 0, 0);
        }
      }
      __builtin_amdgcn_s_setprio(0);
      // online softmax for this nf-pair (defer-max THR=8); interleaves with
      // the next nf-pair's MFMA issue on the VALU pipe
#pragma unroll
      for (int mi = 0; mi < 4; ++mi)
#pragma unroll
        for (int r = 0; r < 4; ++r) {
          int s8 = mi * 4 + r;
          float v0 = acc[mi][2 * nfp][r], v1 = acc[mi][2 * nfp + 1][r];
          float mx = fmaxf(v0, v1);
          float mo = mrun[s8];
          if (mx > mo + 8.f) {
            srun[s8] *= __expf(mo - mx);
            mo = mx;
            mrun[s8] = mx;
          }
          srun[s8] += __expf(v0 - mo) + __expf(v1 - mo);
        }
    }
    __builtin_amdgcn_s_barrier();      // all waves done reading buf[t&1]
    CFENCE();
    if (t + 2 < NT) stage(t + 2);      // overwrite just-consumed buffer; stays in flight
  }

  // merge (m,s) across the 16 lanes holding each row, write per-chunk partials
#pragma unroll
  for (int mi = 0; mi < 4; ++mi)
#pragma unroll
    for (int r = 0; r < 4; ++r) {
      int s8 = mi * 4 + r;
      float m = mrun[s8], s = srun[s8];
#pragma unroll
      for (int msk = 1; msk < 16; msk <<= 1) {
        float mo = __shfl_xor(m, msk);
        float so = __shfl_xor(s, msk);
        float mn = fmaxf(m, mo);
        s = s * __expf(m - mn) + so * __expf(mo - mn);
        m = mn;
      }
      if (l15 == 0) {
        int row = rowbase + mi * 16 + lk16 * 4 + r;
        mpart[blockIdx.y * NTOT + row] = m;
        spart[blockIdx.y * NTOT + row] = s;
      }
    }
}

// ---------- kernel 5a: per-row lse - pos, block partial sums (32 blocks) ----------
__global__ __launch_bounds__(256) void finalize1_kernel(const float* __restrict__ pos,
                                                        const float* __restrict__ mpart,
                                                        const float* __restrict__ spart,
                                                        float* __restrict__ partial) {
  __shared__ float red[4];
  int row = blockIdx.x * 256 + threadIdx.x;
  float m = -1e30f;
#pragma unroll
  for (int c = 0; c < NCHUNK; ++c) m = fmaxf(m, mpart[c * NTOT + row]);
  float s = 0.f;
#pragma unroll
  for (int c = 0; c < NCHUNK; ++c) s += spart[c * NTOT + row] * __expf(mpart[c * NTOT + row] - m);
  float v = m + logf(s) - pos[row];
#pragma unroll
  for (int msk = 1; msk < 64; msk <<= 1) v += __shfl_xor(v, msk);
  if ((threadIdx.x & 63) == 0) red[threadIdx.x >> 6] = v;
  __syncthreads();
  if (threadIdx.x == 0) partial[blockIdx.x] = red[0] + red[1] + red[2] + red[3];
}

// ---------- kernel 5b: final scalar ----------
__global__ __launch_bounds__(64) void finalize2_kernel(const float* __restrict__ partial,
                                                       float* __restrict__ out) {
  int lane = threadIdx.x;
  float v = lane < 32 ? partial[lane] : 0.f;
#pragma unroll
  for (int msk = 1; msk < 64; msk <<= 1) v += __shfl_xor(v, msk);
  if (lane == 0) out[0] = v / (float)NTOT - logf((float)NTOT);
}

extern "C" void kernel_launch(void* const* d_in, const int* in_sizes, int n_in,
                              void* d_out, int out_size, void* d_ws, size_t ws_size,
                              hipStream_t stream) {
  const float* f1 = (const float*)d_in[0];
  const float* f2 = (const float*)d_in[1];
  const float* W = (const float*)d_in[2];
  const float* bias = (const float*)d_in[3];
  const int* prs = (const int*)d_in[4];
  const int* prt = (const int*)d_in[5];
  float* out = (float*)d_out;

  char* ws = (char*)d_ws;
  short* Wt = (short*)(ws);                                  // 256 KB @ 0
  short* emb1 = (short*)(ws + 262144);                       // 4 MB
  short* emb2 = (short*)(ws + 262144 + 4194304);             // 4 MB
  float* pos = (float*)(ws + 8650752);                       // 32 KB
  float* mpart = (float*)(ws + 8683520);                     // 512 KB
  float* spart = (float*)(ws + 9207808);                     // 512 KB
  float* partial = (float*)(ws + 9732096);                   // 128 B

  prep_w_kernel<<<(DF * DIN) / 256, 256, 0, stream>>>(W, Wt);
  proj_kernel<<<dim3(NTOT / PBM, 2), 256, 0, stream>>>(f1, f2, Wt, bias, emb1, emb2);
  positive_kernel<<<NTOT, 64, 0, stream>>>(emb1, emb2, prs, prt, pos);
  negative_kernel<<<dim3(NTOT / NBM, NCHUNK), 256, 0, stream>>>(emb1, emb2, mpart, spart);
  finalize1_kernel<<<32, 256, 0, stream>>>(pos, mpart, spart, partial);
  finalize2_kernel<<<1, 64, 0, stream>>>(partial, out);
}

// Round 4
// 93.964 us; speedup vs baseline: 1.1964x; 1.1393x over previous
//
#include <hip/hip_runtime.h>
#include <hip/hip_bf16.h>
#include <math.h>

#define DIN 512
#define DF 256
#define LSEQ 1024
#define NTOT 8192

typedef __attribute__((ext_vector_type(8))) short short8;
typedef __attribute__((ext_vector_type(4))) short short4v;
typedef __attribute__((ext_vector_type(4))) float f32x4;

__device__ __forceinline__ short f2bf(float x) {
  union { float f; unsigned u; } un; un.f = x;
  unsigned r = un.u + 0x7fffu + ((un.u >> 16) & 1u);  // RNE (inputs finite)
  return (short)(r >> 16);
}
__device__ __forceinline__ float bf2f(short s) {
  union { unsigned u; float f; } un; un.u = ((unsigned)(unsigned short)s) << 16;
  return un.f;
}

typedef __attribute__((address_space(1))) const unsigned char AS1c;
typedef __attribute__((address_space(3))) unsigned char AS3;
__device__ __forceinline__ void gload16(const void* g, void* l) {
  __builtin_amdgcn_global_load_lds((AS1c*)g, (AS3*)l, 16, 0, 0);
}
#define CFENCE() asm volatile("" ::: "memory")

// ---------- kernel 1: W [DIN][DF] f32 -> Wt [DF][DIN] bf16 ----------
__global__ __launch_bounds__(256) void prep_w_kernel(const float* __restrict__ W,
                                                     short* __restrict__ Wt) {
  int idx = blockIdx.x * 256 + threadIdx.x;
  int c = idx >> 9;
  int k = idx & (DIN - 1);
  Wt[idx] = f2bf(W[(size_t)k * DF + c]);
}

// ---------- kernel 2: projection emb = relu(feat @ W + b), bf16 out ----------
// HBM-bound (64MB f32 feature reads): ~12us floor. BM=64, full 256 cols, BK=64.
#define PBM 64
#define PBK 64
#define PROW 72   // padded LDS row in shorts: 144B stride -> 2-lane/bank (free)

__global__ __launch_bounds__(256) void proj_kernel(const float* __restrict__ f1,
                                                   const float* __restrict__ f2,
                                                   const short* __restrict__ Wt,
                                                   const float* __restrict__ bias,
                                                   short* __restrict__ emb1,
                                                   short* __restrict__ emb2) {
  const float* feat = blockIdx.y ? f2 : f1;
  short* emb = blockIdx.y ? emb2 : emb1;
  __shared__ short ldsA[PBM * PROW];
  __shared__ short ldsB[DF * PROW];
  const int tid = threadIdx.x;
  const int lane = tid & 63, wv = tid >> 6;
  const int wrow = (wv & 1) * 32, wcol = (wv >> 1) * 128;
  const int l15 = lane & 15, lk = (lane >> 4) * 8;
  const int rowbase = blockIdx.x * PBM;

  f32x4 acc[2][8];
#pragma unroll
  for (int mi = 0; mi < 2; ++mi)
#pragma unroll
    for (int nf = 0; nf < 8; ++nf) acc[mi][nf] = f32x4{0.f, 0.f, 0.f, 0.f};

  for (int kb = 0; kb < DIN; kb += PBK) {
    __syncthreads();
#pragma unroll
    for (int i = 0; i < 4; ++i) {
      int flat = tid * 4 + i;
      int r = flat >> 4, kq = (flat & 15) * 4;
      f32x4 v = *(const f32x4*)(feat + (size_t)(rowbase + r) * DIN + kb + kq);
      short4v h;
      h[0] = f2bf(v[0]); h[1] = f2bf(v[1]); h[2] = f2bf(v[2]); h[3] = f2bf(v[3]);
      *(short4v*)(ldsA + r * PROW + kq) = h;
    }
#pragma unroll
    for (int i = 0; i < 8; ++i) {
      int c = tid, kq = i * 8;
      short8 v = *(const short8*)(Wt + (size_t)c * DIN + kb + kq);
      *(short8*)(ldsB + c * PROW + kq) = v;
    }
    __syncthreads();
#pragma unroll
    for (int kk = 0; kk < 2; ++kk) {
      short8 af[2], bf[8];
#pragma unroll
      for (int mi = 0; mi < 2; ++mi)
        af[mi] = *(const short8*)(ldsA + (wrow + mi * 16 + l15) * PROW + kk * 32 + lk);
#pragma unroll
      for (int nf = 0; nf < 8; ++nf)
        bf[nf] = *(const short8*)(ldsB + (wcol + nf * 16 + l15) * PROW + kk * 32 + lk);
#pragma unroll
      for (int mi = 0; mi < 2; ++mi)
#pragma unroll
        for (int nf = 0; nf < 8; ++nf)
          acc[mi][nf] = __builtin_amdgcn_mfma_f32_16x16x32_bf16(af[mi], bf[nf], acc[mi][nf], 0, 0, 0);
    }
  }
  const int r4 = (lane >> 4) * 4;
#pragma unroll
  for (int mi = 0; mi < 2; ++mi) {
    int row0 = rowbase + wrow + mi * 16 + r4;
#pragma unroll
    for (int nf = 0; nf < 8; ++nf) {
      int col = wcol + nf * 16 + l15;
      float bb = bias[col];
#pragma unroll
      for (int r = 0; r < 4; ++r) {
        float v = acc[mi][nf][r] + bb;
        v = v > 0.f ? v : 0.f;
        emb[(size_t)(row0 + r) * DF + col] = f2bf(v);
      }
    }
  }
}

// ---------- kernel 3: positive = dot(e1,e2) + banded diag means ----------
__global__ __launch_bounds__(64) void positive_kernel(const short* __restrict__ emb1,
                                                      const short* __restrict__ emb2,
                                                      const int* __restrict__ prs,
                                                      const int* __restrict__ prt,
                                                      float* __restrict__ pos) {
  const int row = blockIdx.x;
  const int b = row >> 10, j = row & (LSEQ - 1);
  const int lane = threadIdx.x;
  const int rs = prs[0], rt = prt[0];
  float a1[4], a2[4];
  {
    short4v v1 = *(const short4v*)(emb1 + (size_t)row * DF + lane * 4);
    short4v v2 = *(const short4v*)(emb2 + (size_t)row * DF + lane * 4);
#pragma unroll
    for (int i = 0; i < 4; ++i) { a1[i] = bf2f(v1[i]); a2[i] = bf2f(v2[i]); }
  }
  float dot12 = 0.f, p11 = 0.f, p22 = 0.f, p12 = 0.f;
#pragma unroll
  for (int i = 0; i < 4; ++i) dot12 += a1[i] * a2[i];
  int rmax = rs > rt ? rs : rt;
  for (int d = -rmax; d <= rmax; ++d) {
    int k = j + d;
    if (k < 0 || k >= LSEQ) continue;
    size_t koff = (size_t)(b * LSEQ + k) * DF + lane * 4;
    short4v w1 = *(const short4v*)(emb1 + koff);
    short4v w2 = *(const short4v*)(emb2 + koff);
    float d11 = 0.f, d22 = 0.f, d12 = 0.f;
#pragma unroll
    for (int i = 0; i < 4; ++i) {
      float e1k = bf2f(w1[i]), e2k = bf2f(w2[i]);
      d11 += a1[i] * e1k;
      d22 += a2[i] * e2k;
      d12 += a1[i] * e2k;
    }
    if (d >= -rs && d <= rs) { p11 += d11; p22 += d22; }
    if (d >= -rt && d <= rt) { p12 += d12; }
  }
#pragma unroll
  for (int m = 1; m < 64; m <<= 1) {
    dot12 += __shfl_xor(dot12, m);
    p11 += __shfl_xor(p11, m);
    p22 += __shfl_xor(p22, m);
    p12 += __shfl_xor(p12, m);
  }
  if (lane == 0) {
    float res = dot12;
    if (rs > 0) {
      int lo = j - rs < 0 ? 0 : j - rs;
      int hi = j + rs > LSEQ - 1 ? LSEQ - 1 : j + rs;
      res += (p11 + p22) / (float)(hi - lo + 1);
    }
    if (rt > 0) {
      int lo = j - rt < 0 ? 0 : j - rt;
      int hi = j + rt > LSEQ - 1 ? LSEQ - 1 : j + rt;
      res += p12 / (float)(hi - lo + 1);
    }
    pos[row] = res;
  }
}

// ---------- kernel 4: flash-style row logsumexp of e1 @ e2^T ----------
// 128 rows/block, 4 waves x 32 rows; A (K=256) in regs = 64 VGPR/wave.
// B tile 32 cols in [kblk][col] LDS layout: frag reads = 1 lane base + static
// offset:N immediates, conflict-free, no swizzle VALU. Staged by global_load_lds
// with transposed (strided, L2-hit) source. 2-deep prefetch, counted vmcnt(4),
// raw barriers, branchless online softmax. 3 blocks/CU (LDS 32KB, VGPR<=170).
#define NBM 128
#define NBN 32
#define NCHUNK 16
#define CHW (NTOT / NCHUNK)   // 512
#define NT (CHW / NBN)        // 16

__global__ __launch_bounds__(256, 3) void negative_kernel(const short* __restrict__ e1,
                                                          const short* __restrict__ e2,
                                                          float* __restrict__ mpart,
                                                          float* __restrict__ spart) {
  __shared__ short ldsB[2][NBN * DF];   // 2 x 16KB, granule (kblk*32+col)
  const int tid = threadIdx.x;
  const int lane = tid & 63, wv = tid >> 6;
  const int l15 = lane & 15, lk16 = lane >> 4;
  const int rowbase = blockIdx.x * NBM + wv * 32;
  const short* colbase = e2 + (size_t)(blockIdx.y * CHW) * DF;

  // per-thread invariant staging offsets: granule G = i*256+tid ->
  // col = tid&31, kblk = i*8 + (tid>>5); src shorts = col*DF + kblk*8
  const int src_off = (tid & 31) * DF + (tid >> 5) * 8;
  const int dst_off = wv * 512;   // + i*2048 shorts

  auto stage = [&](int tt) {
    const short* nb = colbase + (size_t)tt * NBN * DF + src_off;
    short* db = (short*)ldsB[tt & 1] + dst_off;
#pragma unroll
    for (int i = 0; i < 4; ++i)
      gload16(nb + i * 64, db + i * 2048);
  };

  stage(0);
  CFENCE();
  // A fragments: 2 m-frags x 8 k-steps (issued between stage0/stage1 so
  // vmcnt(4) at t=0 implies stage0 + A complete)
  short8 a[2][8];
#pragma unroll
  for (int mi = 0; mi < 2; ++mi)
#pragma unroll
    for (int ks = 0; ks < 8; ++ks)
      a[mi][ks] = *(const short8*)(e1 + (size_t)(rowbase + mi * 16 + l15) * DF + ks * 32 + lk16 * 8);
  CFENCE();
  stage(1);
  CFENCE();

  float mrun[8], srun[8];
#pragma unroll
  for (int i = 0; i < 8; ++i) { mrun[i] = -1e30f; srun[i] = 0.f; }

  for (int t = 0; t < NT; ++t) {
    if (t < NT - 1) asm volatile("s_waitcnt vmcnt(4)" ::: "memory");
    else            asm volatile("s_waitcnt vmcnt(0)" ::: "memory");
    __builtin_amdgcn_s_barrier();      // buf[t&1] fully staged for all waves
    const short* bbase = (const short*)ldsB[t & 1] + lk16 * 256 + l15 * 8;

    f32x4 acc[2][2];
#pragma unroll
    for (int mi = 0; mi < 2; ++mi)
#pragma unroll
      for (int nf = 0; nf < 2; ++nf) acc[mi][nf] = f32x4{0.f, 0.f, 0.f, 0.f};

    __builtin_amdgcn_s_setprio(1);
#pragma unroll
    for (int ks = 0; ks < 8; ++ks) {
      short8 b0 = *(const short8*)(bbase + ks * 1024);
      short8 b1 = *(const short8*)(bbase + ks * 1024 + 128);
#pragma unroll
      for (int mi = 0; mi < 2; ++mi) {
        acc[mi][0] = __builtin_amdgcn_mfma_f32_16x16x32_bf16(a[mi][ks], b0, acc[mi][0], 0, 0, 0);
        acc[mi][1] = __builtin_amdgcn_mfma_f32_16x16x32_bf16(a[mi][ks], b1, acc[mi][1], 0, 0, 0);
      }
    }
    __builtin_amdgcn_s_setprio(0);

    // branchless online softmax (always-rescale; exp(0)=1 in common case)
#pragma unroll
    for (int mi = 0; mi < 2; ++mi)
#pragma unroll
      for (int r = 0; r < 4; ++r) {
        int s8 = mi * 4 + r;
        float v0 = acc[mi][0][r], v1 = acc[mi][1][r];
        float mo = mrun[s8];
        float mn = fmaxf(mo, fmaxf(v0, v1));
        mrun[s8] = mn;
        srun[s8] = srun[s8] * __expf(mo - mn) + __expf(v0 - mn) + __expf(v1 - mn);
      }
    __builtin_amdgcn_s_barrier();      // all waves done reading buf[t&1]
    CFENCE();
    if (t + 2 < NT) stage(t + 2);      // refill just-consumed buffer; stays in flight
  }

  // merge (m,s) across the 16 lanes holding each row, write per-chunk partials
#pragma unroll
  for (int mi = 0; mi < 2; ++mi)
#pragma unroll
    for (int r = 0; r < 4; ++r) {
      int s8 = mi * 4 + r;
      float m = mrun[s8], s = srun[s8];
#pragma unroll
      for (int msk = 1; msk < 16; msk <<= 1) {
        float mo = __shfl_xor(m, msk);
        float so = __shfl_xor(s, msk);
        float mn = fmaxf(m, mo);
        s = s * __expf(m - mn) + so * __expf(mo - mn);
        m = mn;
      }
      if (l15 == 0) {
        int row = rowbase + mi * 16 + lk16 * 4 + r;
        mpart[blockIdx.y * NTOT + row] = m;
        spart[blockIdx.y * NTOT + row] = s;
      }
    }
}

// ---------- kernel 5a: per-row lse - pos, block partial sums (32 blocks) ----------
__global__ __launch_bounds__(256) void finalize1_kernel(const float* __restrict__ pos,
                                                        const float* __restrict__ mpart,
                                                        const float* __restrict__ spart,
                                                        float* __restrict__ partial) {
  __shared__ float red[4];
  int row = blockIdx.x * 256 + threadIdx.x;
  float m = -1e30f;
#pragma unroll
  for (int c = 0; c < NCHUNK; ++c) m = fmaxf(m, mpart[c * NTOT + row]);
  float s = 0.f;
#pragma unroll
  for (int c = 0; c < NCHUNK; ++c) s += spart[c * NTOT + row] * __expf(mpart[c * NTOT + row] - m);
  float v = m + logf(s) - pos[row];
#pragma unroll
  for (int msk = 1; msk < 64; msk <<= 1) v += __shfl_xor(v, msk);
  if ((threadIdx.x & 63) == 0) red[threadIdx.x >> 6] = v;
  __syncthreads();
  if (threadIdx.x == 0) partial[blockIdx.x] = red[0] + red[1] + red[2] + red[3];
}

// ---------- kernel 5b: final scalar ----------
__global__ __launch_bounds__(64) void finalize2_kernel(const float* __restrict__ partial,
                                                       float* __restrict__ out) {
  int lane = threadIdx.x;
  float v = lane < 32 ? partial[lane] : 0.f;
#pragma unroll
  for (int msk = 1; msk < 64; msk <<= 1) v += __shfl_xor(v, msk);
  if (lane == 0) out[0] = v / (float)NTOT - logf((float)NTOT);
}

extern "C" void kernel_launch(void* const* d_in, const int* in_sizes, int n_in,
                              void* d_out, int out_size, void* d_ws, size_t ws_size,
                              hipStream_t stream) {
  const float* f1 = (const float*)d_in[0];
  const float* f2 = (const float*)d_in[1];
  const float* W = (const float*)d_in[2];
  const float* bias = (const float*)d_in[3];
  const int* prs = (const int*)d_in[4];
  const int* prt = (const int*)d_in[5];
  float* out = (float*)d_out;

  char* ws = (char*)d_ws;
  short* Wt = (short*)(ws);                                  // 256 KB @ 0
  short* emb1 = (short*)(ws + 262144);                       // 4 MB
  short* emb2 = (short*)(ws + 262144 + 4194304);             // 4 MB
  float* pos = (float*)(ws + 8650752);                       // 32 KB
  float* mpart = (float*)(ws + 8683520);                     // 512 KB
  float* spart = (float*)(ws + 9207808);                     // 512 KB
  float* partial = (float*)(ws + 9732096);                   // 128 B

  prep_w_kernel<<<(DF * DIN) / 256, 256, 0, stream>>>(W, Wt);
  proj_kernel<<<dim3(NTOT / PBM, 2), 256, 0, stream>>>(f1, f2, Wt, bias, emb1, emb2);
  positive_kernel<<<NTOT, 64, 0, stream>>>(emb1, emb2, prs, prt, pos);
  negative_kernel<<<dim3(NTOT / NBM, NCHUNK), 256, 0, stream>>>(emb1, emb2, mpart, spart);
  finalize1_kernel<<<32, 256, 0, stream>>>(pos, mpart, spart, partial);
  finalize2_kernel<<<1, 64, 0, stream>>>(partial, out);
}